// Round 8
// baseline (222.863 us; speedup 1.0000x reference)
//
#include <hip/hip_runtime.h>
#include <math.h>

#define NPIX 4096
#define AG __HIP_MEMORY_SCOPE_AGENT

// ---------------- workspace layout (floats) ----------------
#define W_POS   0
#define W_SN    12288
#define W_MT    24576   // 160
#define W_OUTS  24736   // 12288
#define W_STAT  37024   // 32: mu[16], rsig[16]
#define W_PB    37056   // ---- zero region ----
#define W_QKV   49344
#define W_OUTP  61632
#define W_MOM   73920   // 40
#define W_BAR   73960   // 16 ints (memset to 0 each launch)
#define NZERO   36904   // W_PB .. W_MOM+40

__device__ const int dT12[9]  = {0,1,2, 1,3,4, 2,4,5};
__device__ const int dT23[18] = {0,1,2, 1,3,4, 2,4,5, 3,6,7, 4,7,8, 5,8,9};
__device__ const int dT34[30] = {0,1,2, 1,3,4, 2,4,5, 3,6,7, 4,7,8, 5,8,9,
                                 6,10,11, 7,11,12, 8,12,13, 9,13,14};
__device__ const float dC2[6]  = {1,2,2,1,2,1};
__device__ const float dC3[10] = {1,3,3,3,6,3,1,3,3,1};
__device__ const float dC4[15] = {1,4,4,6,12,6,4,12,12,4,1,4,6,4,1};

__device__ __forceinline__ float ald(const float* p) {
    return __hip_atomic_load((float*)p, __ATOMIC_RELAXED, AG);
}
__device__ __forceinline__ void ast(float* p, float v) {
    __hip_atomic_store(p, v, __ATOMIC_RELAXED, AG);
}
__device__ __forceinline__ void drain() {
    asm volatile("s_waitcnt vmcnt(0)" ::: "memory");
}

__device__ __forceinline__ float gelu_exact(float x) {
    return 0.5f * x * (1.0f + erff(x * 0.70710678118654752440f));
}

__device__ __forceinline__ float conv3_tap(const float* __restrict__ src,
                                           const float* __restrict__ w,
                                           int o, int y, int x) {
    float acc = 0.f;
#pragma unroll
    for (int ci = 0; ci < 3; ++ci) {
#pragma unroll
        for (int dy = 0; dy < 3; ++dy) {
            int yy = y + dy - 1;
            if (yy < 0 || yy >= 64) continue;
#pragma unroll
            for (int dx = 0; dx < 3; ++dx) {
                int xx = x + dx - 1;
                if (xx < 0 || xx >= 64) continue;
                acc = fmaf(src[ci*NPIX + yy*64 + xx], w[o*27 + ci*9 + dy*3 + dx], acc);
            }
        }
    }
    return acc;
}

__device__ __forceinline__ void build34(float a0, float a1, float a2, float* A) {
    A[0]=a0; A[1]=a1; A[2]=a2;
    A[3]=a0*a0; A[4]=a0*a1; A[5]=a0*a2; A[6]=a1*a1; A[7]=a1*a2; A[8]=a2*a2;
    A[9]=A[3]*a0; A[10]=A[3]*a1; A[11]=A[3]*a2; A[12]=A[4]*a1; A[13]=A[4]*a2;
    A[14]=A[5]*a2; A[15]=A[6]*a1; A[16]=A[6]*a2; A[17]=A[7]*a2; A[18]=A[8]*a2;
    A[19]=A[9]*a0; A[20]=A[9]*a1; A[21]=A[9]*a2; A[22]=A[10]*a1; A[23]=A[10]*a2;
    A[24]=A[11]*a2; A[25]=A[12]*a1; A[26]=A[12]*a2; A[27]=A[13]*a2; A[28]=A[14]*a2;
    A[29]=A[15]*a1; A[30]=A[15]*a2; A[31]=A[16]*a2; A[32]=A[17]*a2; A[33]=A[18]*a2;
}

// fence-free grid barrier: all data traffic is agent-coherent (sc1 atomics),
// so arrival only needs vmcnt-drain + relaxed counter. No wbl2 / inv.
__device__ __forceinline__ void gbar(int* bar, int idx) {
    drain();
    __syncthreads();
    if (threadIdx.x == 0) {
        __hip_atomic_fetch_add(&bar[idx], 1, __ATOMIC_RELAXED, AG);
        while (__hip_atomic_load(&bar[idx], __ATOMIC_RELAXED, AG) < (int)gridDim.x)
            __builtin_amdgcn_s_sleep(2);
    }
    __syncthreads();
}

__global__ __launch_bounds__(256) void fused_dam(
        const float* __restrict__ x,   const float* __restrict__ pew1,
        const float* __restrict__ pew2,
        const float* __restrict__ ew,  const float* __restrict__ eb,
        const float* __restrict__ g1,  const float* __restrict__ b1,
        const float* __restrict__ qpw, const float* __restrict__ ppw,
        const float* __restrict__ ppb, const float* __restrict__ rw,
        const float* __restrict__ rb,  const float* __restrict__ g2,
        const float* __restrict__ b2,  const float* __restrict__ qsw,
        const float* __restrict__ psw, const float* __restrict__ psb,
        const float* __restrict__ pdw1,const float* __restrict__ pdw2,
        float* __restrict__ ws, float* __restrict__ out) {
    __shared__ float smem[17200];
    const int b = blockIdx.x, tid = threadIdx.x;

    float* pos  = ws + W_POS;
    float* sn   = ws + W_SN;
    float* MT   = ws + W_MT;
    float* outs = ws + W_OUTS;
    float* stat = ws + W_STAT;
    float* pb   = ws + W_PB;
    float* qkvp = ws + W_QKV;
    float* outp = ws + W_OUTP;
    float* mom  = ws + W_MOM;
    int*   bar  = (int*)(ws + W_BAR);

    // ================= P1: front conv+LN2 | MT | zero+warm =================
    if (b < 16) {
        float (*t1l)[8][64] = (float(*)[8][64])smem;
        int y0 = b * 4;
        for (int i = tid; i < 1536; i += 256) {
            int c = i >> 9, rr = (i >> 6) & 7, xx = i & 63;
            int yg = y0 - 2 + rr;
            float v = 0.f;
            if (yg >= 0 && yg < 64) v = gelu_exact(conv3_tap(x, pew1, c, yg, xx));
            t1l[c][rr][xx] = v;
        }
        __syncthreads();
        int n = b*256 + tid;
        int yl = tid >> 6, xx = tid & 63;
        int yg = y0 + yl;
        float p[3];
#pragma unroll
        for (int o = 0; o < 3; ++o) {
            float acc = 0.f;
#pragma unroll
            for (int ci = 0; ci < 3; ++ci) {
#pragma unroll
                for (int dy = 0; dy < 3; ++dy) {
                    int yy = yg + dy - 1;
                    if (yy < 0 || yy >= 64) continue;
                    int rl = yl + dy + 1;
#pragma unroll
                    for (int dx = 0; dx < 3; ++dx) {
                        int xc = xx + dx - 1;
                        if (xc < 0 || xc >= 64) continue;
                        acc = fmaf(t1l[ci][rl][xc], pew2[o*27 + ci*9 + dy*3 + dx], acc);
                    }
                }
            }
            p[o] = acc;
        }
        float mu = (p[0] + p[1] + p[2]) * (1.f/3.f);
        float d0 = p[0]-mu, d1 = p[1]-mu, d2 = p[2]-mu;
        float r = rsqrtf((d0*d0 + d1*d1 + d2*d2) * (1.f/3.f) + 1e-5f);
        ast(&pos[n], p[0]); ast(&pos[NPIX+n], p[1]); ast(&pos[2*NPIX+n], p[2]);
        ast(&sn[n],        d0*r*g2[0] + b2[0]);
        ast(&sn[NPIX+n],   d1*r*g2[1] + b2[1]);
        ast(&sn[2*NPIX+n], d2*r*g2[2] + b2[2]);
    } else if (b == 16) {
        if (tid < 144) {
            int isT = tid >= 72;
            int u = isT ? tid - 72 : tid;
            int h = u / 9, i = (u % 9) / 3, j = u % 3;
            float acc = 0.f;
            if (!isT) {   // M_h = Wq_h Wk_h^T / sqrt(32)
                const float* wq = qsw + i*768 + h*32;
                const float* wk = qsw + j*768 + 256 + h*32;
#pragma unroll
                for (int d = 0; d < 32; ++d) acc = fmaf(wq[d], wk[d], acc);
                acc *= 0.17677669529663687f;
            } else {      // T_h = Wv_h Pr_h
                const float* wv = qsw + i*768 + 512 + h*32;
#pragma unroll
                for (int d = 0; d < 32; ++d) acc = fmaf(wv[d], psw[(h*32 + d)*3 + j], acc);
            }
            ast(&MT[tid], acc);
        }
    } else {
        // zero accumulators (agent stores) + warm L3 with weights (plain)
        int gid = (b - 17)*256 + tid;                 // 0..61183
        if (gid < NZERO) ast(ws + W_PB + gid, 0.0f);
        float acc = 0.f;
        for (int i = gid; i < 147456; i += 61184) { float4 v = ((const float4*)ew)[i];  acc += v.x+v.y+v.z+v.w; }
        for (int i = gid; i < 147456; i += 61184) { float4 v = ((const float4*)qpw)[i]; acc += v.x+v.y+v.z+v.w; }
        for (int i = gid; i < 49152;  i += 61184) { float4 v = ((const float4*)ppw)[i]; acc += v.x+v.y+v.z+v.w; }
        for (int i = gid; i < 147456; i += 61184) { float4 v = ((const float4*)rw)[i];  acc += v.x+v.y+v.z+v.w; }
        asm volatile("" :: "v"(acc));
    }
    gbar(bar, 0);

    // ====== P2: embed (96) -> sub-arrive | moments then LN1-stats (16) =====
    if (b < 96) {
        int och = b % 3, ks = b / 3;       // 32 k-splits of 24
        int k0 = ks * 24;
        float* pv = smem;                  // [16][24]
        for (int idx = tid; idx < 384; idx += 256) {
            int t = idx / 24, k = idx % 24;
            int kk = k0 + k;
            int cc = kk >> 8, pp = (kk >> 4) & 15, q = kk & 15;
            int hp = t >> 2, wp = t & 3;
            pv[idx] = ald(&pos[cc*NPIX + (hp*16 + pp)*64 + wp*16 + q]);
        }
        __syncthreads();
        int o = och*256 + tid;
        float4 w4[6];
        const float4* wr = (const float4*)(ew + o*768 + k0);
#pragma unroll
        for (int i = 0; i < 6; ++i) w4[i] = wr[i];
        float acc[16];
#pragma unroll
        for (int t = 0; t < 16; ++t) acc[t] = 0.f;
#pragma unroll
        for (int i = 0; i < 6; ++i) {
#pragma unroll
            for (int t = 0; t < 16; ++t) {
                const float* p4 = &pv[t*24 + i*4];
                acc[t] = fmaf(w4[i].x, p4[0], acc[t]);
                acc[t] = fmaf(w4[i].y, p4[1], acc[t]);
                acc[t] = fmaf(w4[i].z, p4[2], acc[t]);
                acc[t] = fmaf(w4[i].w, p4[3], acc[t]);
            }
        }
#pragma unroll
        for (int t = 0; t < 16; ++t) atomicAdd(&pb[t*768 + o], acc[t]);
        drain();
        __syncthreads();
        if (tid == 0) __hip_atomic_fetch_add(&bar[8], 1, __ATOMIC_RELAXED, AG);
    } else if (b < 112) {
        // moments of sn (34 monomial sums)
        int n = (b - 96)*256 + tid;
        float B[34];
        build34(ald(&sn[n]), ald(&sn[NPIX+n]), ald(&sn[2*NPIX+n]), B);
        int lane = tid & 63, wid = tid >> 6;
#pragma unroll
        for (int u = 0; u < 34; ++u) {
            float t = B[u];
#pragma unroll
            for (int o = 1; o <= 32; o <<= 1) t += __shfl_xor(t, o);
            if (lane == 0) smem[wid*34 + u] = t;
        }
        __syncthreads();
        if (tid < 34)
            atomicAdd(&mom[tid], smem[tid] + smem[34+tid] + smem[68+tid] + smem[102+tid]);
        // wait for all 96 embed blocks, then compute LN1 stats (token = b-96)
        if (tid == 0) {
            while (__hip_atomic_load(&bar[8], __ATOMIC_RELAXED, AG) < 96)
                __builtin_amdgcn_s_sleep(2);
        }
        __syncthreads();
        int t = b - 96;
        float s = 0.f, s2 = 0.f;
#pragma unroll
        for (int r = 0; r < 3; ++r) {
            int o = tid + r*256;
            float v = ald(&pb[t*768 + o]) + eb[o];
            s += v; s2 += v*v;
        }
#pragma unroll
        for (int o = 1; o <= 32; o <<= 1) { s += __shfl_xor(s, o); s2 += __shfl_xor(s2, o); }
        int wid2 = tid >> 6;
        if ((tid & 63) == 0) { smem[256 + wid2] = s; smem[260 + wid2] = s2; }
        __syncthreads();
        if (tid == 0) {
            float S = smem[256]+smem[257]+smem[258]+smem[259];
            float S2 = smem[260]+smem[261]+smem[262]+smem[263];
            float mu = S * (1.f/768.f);
            ast(&stat[t], mu);
            ast(&stat[16 + t], rsqrtf(fmaxf(S2 * (1.f/768.f) - mu*mu, 0.f) + 1e-5f));
        }
    }
    gbar(bar, 1);

    // ====== P3: qkv GEMM w/ on-the-fly LN (96) | pixel-attn polyeval (16) ==
    if (b < 96) {
        int och = b % 3, ks = b / 3;
        int k0 = ks * 24;
        float* ps  = smem;        // [16][24]
        float* smu = smem + 384;  // 16
        float* srs = smem + 400;  // 16
        if (tid < 16) { smu[tid] = ald(&stat[tid]); srs[tid] = ald(&stat[16+tid]); }
        __syncthreads();
        for (int idx = tid; idx < 384; idx += 256) {
            int t = idx / 24, k = idx % 24;
            int kk = k0 + k;
            float raw = ald(&pb[t*768 + kk]) + eb[kk];
            ps[idx] = (raw - smu[t]) * srs[t] * g1[kk] + b1[kk];
        }
        __syncthreads();
        int o = och*256 + tid;
        float acc[16];
#pragma unroll
        for (int t = 0; t < 16; ++t) acc[t] = 0.f;
#pragma unroll
        for (int k = 0; k < 24; ++k) {
            float w = qpw[(k0 + k)*768 + o];
#pragma unroll
            for (int t = 0; t < 16; ++t) acc[t] = fmaf(ps[t*24 + k], w, acc[t]);
        }
#pragma unroll
        for (int t = 0; t < 16; ++t) atomicAdd(&qkvp[t*768 + o], acc[t]);
    } else if (b < 112) {
        float* evmt = smem;          // 144
        float* evDW = smem + 144;    // 34
        float* evNW = smem + 180;    // 60
        if (tid < 144) evmt[tid] = ald(&MT[tid]);
        if (tid < 34) {
            float c;
            if (tid < 3) c = 1.f;
            else if (tid < 9)  c = dC2[tid-3]  * 0.5f;
            else if (tid < 19) c = dC3[tid-9]  * (1.f/6.f);
            else               c = dC4[tid-19] * (1.f/24.f);
            evDW[tid] = c * ald(&mom[tid]);
        }
        if (tid >= 192 && tid < 252) {
            int q = tid - 192; int j = q / 20, u = q % 20;
            float val;
            if (u == 0)       val = ald(&mom[j]);
            else if (u < 4)   val = ald(&mom[3  + dT12[(u-1)*3 + j]]);
            else if (u < 10)  val = (dC2[u-4]  * 0.5f)      * ald(&mom[9  + dT23[(u-4)*3 + j]]);
            else              val = (dC3[u-10] * (1.f/6.f)) * ald(&mom[19 + dT34[(u-10)*3 + j]]);
            evNW[j*20 + u] = val;
        }
        __syncthreads();
        int n = (b-96)*256 + tid;
        float x0 = ald(&sn[n]), x1 = ald(&sn[NPIX+n]), x2 = ald(&sn[2*NPIX+n]);
        float o0 = 0.f, o1 = 0.f, o2 = 0.f;
        for (int h = 0; h < 8; ++h) {
            const float* M = &evmt[h*9];
            float a0 = x0*M[0] + x1*M[3] + x2*M[6];
            float a1 = x0*M[1] + x1*M[4] + x2*M[7];
            float a2 = x0*M[2] + x1*M[5] + x2*M[8];
            float A[34];
            build34(a0, a1, a2, A);
            float den = 4096.f;
#pragma unroll
            for (int u = 0; u < 34; ++u) den = fmaf(A[u], evDW[u], den);
            float num[3];
#pragma unroll
            for (int j = 0; j < 3; ++j) {
                float s = evNW[j*20];
#pragma unroll
                for (int u = 0; u < 19; ++u) s = fmaf(A[u], evNW[j*20 + 1 + u], s);
                num[j] = s;
            }
            float ir = 1.f / den;
            float r0 = num[0]*ir, r1 = num[1]*ir, r2 = num[2]*ir;
            const float* T = &evmt[72 + h*9];
            o0 += r0*T[0] + r1*T[3] + r2*T[6];
            o1 += r0*T[1] + r1*T[4] + r2*T[7];
            o2 += r0*T[2] + r1*T[5] + r2*T[8];
        }
        ast(&outs[n],        o0 + psb[0]);
        ast(&outs[NPIX+n],   o1 + psb[1]);
        ast(&outs[2*NPIX+n], o2 + psb[2]);
    }
    gbar(bar, 2);

    // ====== P4: replicated patch attention + proj slice + recon (96) =======
    if (b < 96) {
        float* qs  = smem;          // [16][771] padded
        float* att = smem + 12336;  // [16][257] padded
        float* scl = smem + 16448;  // 256
        float* ops = smem + 16704;  // [16][24]
        int dch = b % 3, cs = b / 3;
        int c0 = cs * 24;
        for (int idx = tid; idx < 12288; idx += 256) {
            int t = idx / 768, c = idx % 768;
            qs[t*771 + c] = ald(&qkvp[idx]);
        }
        __syncthreads();
        for (int h = 0; h < 8; ++h) {
            {
                int nn = tid >> 4, m = tid & 15;
                const float* q = &qs[nn*771 + h*32];
                const float* k = &qs[m*771 + 256 + h*32];
                float d = 0.f;
#pragma unroll
                for (int dd = 0; dd < 32; ++dd) d = fmaf(q[dd], k[dd], d);
                scl[tid] = d * 0.17677669529663687f;
            }
            __syncthreads();
            if (tid < 16) {
                float* row = &scl[tid*16];
                float mx = row[0];
#pragma unroll
                for (int m = 1; m < 16; ++m) mx = fmaxf(mx, row[m]);
                float s = 0.f;
#pragma unroll
                for (int m = 0; m < 16; ++m) { float e = expf(row[m]-mx); row[m] = e; s += e; }
                float inv = 1.f / s;
#pragma unroll
                for (int m = 0; m < 16; ++m) row[m] *= inv;
            }
            __syncthreads();
#pragma unroll
            for (int r = 0; r < 2; ++r) {
                int idx = tid + r*256;
                int nn = idx >> 5, dd = idx & 31;
                float a = 0.f;
#pragma unroll
                for (int m = 0; m < 16; ++m)
                    a = fmaf(scl[nn*16 + m], qs[m*771 + 512 + h*32 + dd], a);
                att[nn*257 + h*32 + dd] = a;
            }
            __syncthreads();
        }
        // proj slice: ops[t][c] = ppb + att[t][:] . ppw[:, c0+c]
        for (int idx = tid; idx < 384; idx += 256) {
            int t = idx / 24, c = idx % 24;
            float a = ppb[c0 + c];
            for (int m = 0; m < 256; ++m)
                a = fmaf(att[t*257 + m], ppw[m*768 + c0 + c], a);
            ops[idx] = a;
        }
        __syncthreads();
        // recon partial over this c-slice
        int dij = dch*256 + tid;
        float acc[16];
#pragma unroll
        for (int t = 0; t < 16; ++t) acc[t] = 0.f;
#pragma unroll
        for (int c = 0; c < 24; ++c) {
            float w = rw[(c0 + c)*768 + dij];
#pragma unroll
            for (int t = 0; t < 16; ++t) acc[t] = fmaf(ops[t*24 + c], w, acc[t]);
        }
        int d = dij >> 8, i = (dij >> 4) & 15, j = dij & 15;
#pragma unroll
        for (int t = 0; t < 16; ++t) {
            int hp = t >> 2, wp = t & 3;
            atomicAdd(&outp[d*NPIX + (hp*16 + i)*64 + wp*16 + j], acc[t]);
        }
    }
    gbar(bar, 3);

    // ================= P5: combine + final convs (16) ======================
    if (b < 16) {
        float (*t2l)[8][64] = (float(*)[8][64])smem;
        int y0 = b * 4;
        for (int i = tid; i < 1536; i += 256) {
            int c = i >> 9, rr = (i >> 6) & 7, xx = i & 63;
            int yg = y0 - 2 + rr;
            float v = 0.f;
            if (yg >= 0 && yg < 64) {
                float acc = 0.f;
#pragma unroll
                for (int ci = 0; ci < 3; ++ci) {
                    float bias = rb[ci];
#pragma unroll
                    for (int dy = 0; dy < 3; ++dy) {
                        int yy = yg + dy - 1;
                        if (yy < 0 || yy >= 64) continue;
#pragma unroll
                        for (int dx = 0; dx < 3; ++dx) {
                            int xc = xx + dx - 1;
                            if (xc < 0 || xc >= 64) continue;
                            float cb = ald(&outp[ci*NPIX + yy*64 + xc]) + bias
                                     + ald(&outs[ci*NPIX + yy*64 + xc]);
                            acc = fmaf(cb, pdw1[c*27 + ci*9 + dy*3 + dx], acc);
                        }
                    }
                }
                v = gelu_exact(acc);
            }
            t2l[c][rr][xx] = v;
        }
        __syncthreads();
        int yl = tid >> 6, xx = tid & 63;
        int yg = y0 + yl;
#pragma unroll
        for (int o = 0; o < 3; ++o) {
            float acc = 0.f;
#pragma unroll
            for (int ci = 0; ci < 3; ++ci) {
#pragma unroll
                for (int dy = 0; dy < 3; ++dy) {
                    int yy = yg + dy - 1;
                    if (yy < 0 || yy >= 64) continue;
                    int rl = yl + dy + 1;
#pragma unroll
                    for (int dx = 0; dx < 3; ++dx) {
                        int xc = xx + dx - 1;
                        if (xc < 0 || xc >= 64) continue;
                        acc = fmaf(t2l[ci][rl][xc], pdw2[o*27 + ci*9 + dy*3 + dx], acc);
                    }
                }
            }
            out[o*NPIX + yg*64 + xx] = acc;
        }
    }
}

extern "C" void kernel_launch(void* const* d_in, const int* in_sizes, int n_in,
                              void* d_out, int out_size, void* d_ws, size_t ws_size,
                              hipStream_t stream) {
    (void)in_sizes; (void)n_in; (void)out_size; (void)ws_size;
    const float* x    = (const float*)d_in[0];
    const float* pew1 = (const float*)d_in[1];
    const float* pew2 = (const float*)d_in[2];
    const float* ew   = (const float*)d_in[3];
    const float* eb   = (const float*)d_in[4];
    const float* g1   = (const float*)d_in[5];
    const float* b1   = (const float*)d_in[6];
    const float* qpw  = (const float*)d_in[7];
    const float* ppw  = (const float*)d_in[8];
    const float* ppb  = (const float*)d_in[9];
    const float* rw   = (const float*)d_in[10];
    const float* rb   = (const float*)d_in[11];
    const float* g2   = (const float*)d_in[12];
    const float* b2   = (const float*)d_in[13];
    const float* qsw  = (const float*)d_in[14];
    const float* psw  = (const float*)d_in[15];
    const float* psb  = (const float*)d_in[16];
    const float* pdw1 = (const float*)d_in[17];
    const float* pdw2 = (const float*)d_in[18];

    float* ws  = (float*)d_ws;
    float* out = (float*)d_out;

    hipMemsetAsync((char*)d_ws + (size_t)W_BAR*4, 0, 64, stream);
    fused_dam<<<dim3(256), dim3(256), 0, stream>>>(
        x, pew1, pew2, ew, eb, g1, b1, qpw, ppw, ppb, rw, rb, g2, b2,
        qsw, psw, psb, pdw1, pdw2, ws, out);
}